// Round 3
// baseline (115.973 us; speedup 1.0000x reference)
//
#include <hip/hip_runtime.h>

#define NPTS 4096      // points per cloud
#define NB   4         // batch
#define KP   512       // keypoints
#define HUBER_C 0.01f
#define HALF_PTS (NB * NPTS)          // 16384
#define TOT_PTS  (2 * NB * NPTS)      // 32768

// ws layout:
//   [0,            512 KB)  float4 pts4[TOT_PTS]   {x,y,z,|p|^2}, src then tgt
//   [512 KB,       640 KB)  unsigned minarr[TOT_PTS]  (uint-ordered min bits)
//   [640 KB, 640 KB + 64B)  ctrl: [0]=float acc (nc loss), [1]=uint block counter

// ---------------- helpers ----------------

__device__ inline void wave_reduce_add_to(float v, float* target) {
    #pragma unroll
    for (int off = 32; off; off >>= 1) v += __shfl_down(v, off, 64);
    if ((threadIdx.x & 63) == 0) atomicAdd(target, v);
}

__device__ inline float huber_f(float x) {
    return (x < HUBER_C) ? 0.5f * x * x
                         : fmaf(HUBER_C, x, -0.5f * HUBER_C * HUBER_C);
}

// ---------------- kernels ----------------

// grid = HALF_PTS/256 = 64 blocks. Builds pts4, inits minarr, zeroes ctrl.
__global__ __launch_bounds__(256) void prep_kernel(
    const float* __restrict__ srcT, const float* __restrict__ tgtT,
    float4* __restrict__ pts4, unsigned* __restrict__ minarr,
    unsigned* __restrict__ ctrl)
{
    int i = blockIdx.x * 256 + threadIdx.x;    // [0, HALF_PTS)
    int b = i >> 12, j = i & (NPTS - 1);
    const float* s = srcT + b * 3 * NPTS;
    const float* t = tgtT + b * 3 * NPTS;
    float sx = s[j], sy = s[NPTS + j], sz = s[2 * NPTS + j];
    float tx = t[j], ty = t[NPTS + j], tz = t[2 * NPTS + j];
    pts4[i]            = make_float4(sx, sy, sz, fmaf(sx, sx, fmaf(sy, sy, sz * sz)));
    pts4[HALF_PTS + i] = make_float4(tx, ty, tz, fmaf(tx, tx, fmaf(ty, ty, tz * tz)));
    minarr[i] = 0x7F800000u;                  // +inf
    minarr[HALF_PTS + i] = 0x7F800000u;
    if (blockIdx.x == 0 && threadIdx.x < 2) ctrl[threadIdx.x] = 0u;  // acc=0.f, cnt=0
}

// Fused main: blocks [0,512) gal pairwise-min; then knn; then kp.
// Last-arriving block performs the finalize (huber over minarr + out writes).
__global__ __launch_bounds__(256) void main_kernel(
    const float4* __restrict__ pts4, unsigned* __restrict__ minarr,
    const float* __restrict__ skp, const float* __restrict__ tkp,
    const float* __restrict__ R, const float* __restrict__ T,
    const float* __restrict__ aknn, const float* __restrict__ bknn,
    const int* __restrict__ kptr, float* __restrict__ acc,
    unsigned* __restrict__ cnt, float* __restrict__ out,
    int knn_blocks, int knn_quads)
{
    __shared__ float red[4];
    __shared__ int s_last;
    const int bid = blockIdx.x;
    const int tid = threadIdx.x;

    if (bid < 512) {
        // ---- global-align pairwise min ----
        const int dir = bid & 1;                 // 0: queries=src, 1: queries=tgt
        const int b   = (bid >> 1) & 3;
        const int oc  = (bid >> 3) & 7;          // 8 other-stripes of 512
        const int qc  = bid >> 6;                // 8 query-chunks of 512
        const float4* q4 = pts4 + (dir ? HALF_PTS : 0) + b * NPTS;
        const float4* o4 = pts4 + (dir ? 0 : HALF_PTS) + b * NPTS + oc * 512;
        const int qi0 = qc * 512 + tid;
        const int qi1 = qi0 + 256;
        const float4 qa = q4[qi0];
        const float4 qb = q4[qi1];
        const float ax = -2.0f * qa.x, ay = -2.0f * qa.y, az = -2.0f * qa.z;
        const float bx = -2.0f * qb.x, by = -2.0f * qb.y, bz = -2.0f * qb.z;
        float ma = 3.0e38f, mb = 3.0e38f;
        #pragma unroll 4
        for (int j = 0; j < 512; j += 2) {
            float4 o0 = o4[j], o1 = o4[j + 1];   // block-uniform -> broadcast load
            float ta0 = fmaf(o0.x, ax, fmaf(o0.y, ay, fmaf(o0.z, az, o0.w)));
            float ta1 = fmaf(o1.x, ax, fmaf(o1.y, ay, fmaf(o1.z, az, o1.w)));
            ma = fminf(ma, fminf(ta0, ta1));     // v_min3_f32
            float tb0 = fmaf(o0.x, bx, fmaf(o0.y, by, fmaf(o0.z, bz, o0.w)));
            float tb1 = fmaf(o1.x, bx, fmaf(o1.y, by, fmaf(o1.z, bz, o1.w)));
            mb = fminf(mb, fminf(tb0, tb1));
        }
        const float da = qa.w + ma;              // >= 0: uint atomicMin order-safe
        const float db = qb.w + mb;
        unsigned* marr = minarr + (dir * NB + b) * NPTS;
        atomicMin(&marr[qi0], __float_as_uint(da));
        atomicMin(&marr[qi1], __float_as_uint(db));
    } else if (bid < 512 + knn_blocks) {
        // ---- knn consensus: sum((a-b)^2)/k ----
        int i = (bid - 512) * 256 + tid;
        float sum = 0.0f;
        if (i < knn_quads) {
            float4 va = ((const float4*)aknn)[i];
            float4 vb = ((const float4*)bknn)[i];
            float dx = va.x - vb.x, dy = va.y - vb.y;
            float dz = va.z - vb.z, dw = va.w - vb.w;
            sum = fmaf(dx, dx, fmaf(dy, dy, fmaf(dz, dz, dw * dw)));
        }
        float scale = 1.0f / (float)(*kptr);
        wave_reduce_add_to(sum * scale, acc);
    } else {
        // ---- keypoints: sum((R@s + t - g)^2) ----
        int i = (bid - 512 - knn_blocks) * 256 + tid;   // [0, NB*KP)
        int b = i >> 9;
        int n = i & (KP - 1);
        const float* r = R + b * 9;
        const float* t = T + b * 3;
        const float* s = skp + b * 3 * KP;
        const float* g = tkp + b * 3 * KP;
        float sx = s[n], sy = s[KP + n], sz = s[2 * KP + n];
        float sum = 0.0f;
        #pragma unroll
        for (int d = 0; d < 3; ++d) {
            float v = fmaf(r[d*3+0], sx, fmaf(r[d*3+1], sy, fmaf(r[d*3+2], sz, t[d])))
                      - g[d * KP + n];
            sum = fmaf(v, v, sum);
        }
        wave_reduce_add_to(sum, out == out ? acc : acc);  // acc
    }

    // ---- completion counter: last block finalizes ----
    __syncthreads();                     // all block mem ops issued & drained
    if (tid == 0) {
        __threadfence();                 // release: publish our atomics
        unsigned old = atomicAdd(cnt, 1u);
        s_last = (old == (unsigned)gridDim.x - 1u) ? 1 : 0;
    }
    __syncthreads();
    if (!s_last) return;

    __threadfence();                     // acquire: see all blocks' results
    const uint4* m4 = (const uint4*)minarr;
    float sum = 0.0f;
    #pragma unroll
    for (int r = 0; r < 32; ++r) {       // 256 thr * 32 * uint4 = 32768 mins
        uint4 v = m4[r * 256 + tid];
        sum += huber_f(__uint_as_float(v.x)) + huber_f(__uint_as_float(v.y))
             + huber_f(__uint_as_float(v.z)) + huber_f(__uint_as_float(v.w));
    }
    #pragma unroll
    for (int off = 32; off; off >>= 1) sum += __shfl_down(sum, off, 64);
    if ((tid & 63) == 0) red[tid >> 6] = sum;
    __syncthreads();
    if (tid == 0) {
        out[1] = red[0] + red[1] + red[2] + red[3];  // gal
        out[0] = *acc;                               // neighborhood consensus
    }
}

// ---------------- fallback (no workspace) ----------------

__global__ void zero_out_kernel(float* __restrict__ out) {
    if (threadIdx.x < 2) out[threadIdx.x] = 0.0f;
}

__global__ __launch_bounds__(256) void gal_direct_kernel(
    const float* __restrict__ srcT, const float* __restrict__ tgtT,
    float* __restrict__ gal_out)
{
    const int dir = blockIdx.y >> 2;
    const int b   = blockIdx.y & 3;
    const float* qb = (dir ? tgtT : srcT) + b * 3 * NPTS;
    const float* ob = (dir ? srcT : tgtT) + b * 3 * NPTS;
    const int qi = blockIdx.x * 256 + threadIdx.x;
    const float qx = qb[qi], qy = qb[NPTS + qi], qz = qb[2 * NPTS + qi];
    float m = 3.0e38f;
    #pragma unroll 4
    for (int j = 0; j < NPTS; ++j) {
        float dx = qx - ob[j], dy = qy - ob[NPTS + j], dz = qz - ob[2 * NPTS + j];
        m = fminf(m, fmaf(dx, dx, fmaf(dy, dy, dz * dz)));
    }
    wave_reduce_add_to(huber_f(m), gal_out);
}

__global__ __launch_bounds__(256) void kp_kernel(
    const float* __restrict__ skp, const float* __restrict__ tkp,
    const float* __restrict__ R, const float* __restrict__ T,
    float* __restrict__ acc)
{
    int i = blockIdx.x * 256 + threadIdx.x;
    int b = i >> 9, n = i & (KP - 1);
    const float* r = R + b * 9;
    const float* t = T + b * 3;
    const float* s = skp + b * 3 * KP;
    const float* g = tkp + b * 3 * KP;
    float sx = s[n], sy = s[KP + n], sz = s[2 * KP + n];
    float sum = 0.0f;
    #pragma unroll
    for (int d = 0; d < 3; ++d) {
        float v = fmaf(r[d*3+0], sx, fmaf(r[d*3+1], sy, fmaf(r[d*3+2], sz, t[d])))
                  - g[d * KP + n];
        sum = fmaf(v, v, sum);
    }
    wave_reduce_add_to(sum, acc);
}

__global__ __launch_bounds__(256) void knn_kernel(
    const float* __restrict__ a, const float* __restrict__ b,
    const int* __restrict__ kptr, float* __restrict__ acc, int quads)
{
    int i = blockIdx.x * 256 + threadIdx.x;
    float sum = 0.0f;
    if (i < quads) {
        float4 va = ((const float4*)a)[i];
        float4 vb = ((const float4*)b)[i];
        float dx = va.x - vb.x, dy = va.y - vb.y;
        float dz = va.z - vb.z, dw = va.w - vb.w;
        sum = fmaf(dx, dx, fmaf(dy, dy, fmaf(dz, dz, dw * dw)));
    }
    float scale = 1.0f / (float)(*kptr);
    wave_reduce_add_to(sum * scale, acc);
}

// ---------------- launch ----------------

extern "C" void kernel_launch(void* const* d_in, const int* in_sizes, int n_in,
                              void* d_out, int out_size, void* d_ws, size_t ws_size,
                              hipStream_t stream) {
    const float* skp  = (const float*)d_in[0];   // (B,3,KP)
    const float* tkp  = (const float*)d_in[1];   // (B,3,KP)
    const float* R    = (const float*)d_in[2];   // (B,3,3)
    const float* T    = (const float*)d_in[3];   // (B,3)
    const float* aknn = (const float*)d_in[4];   // (B,3,KP,K)
    const float* bknn = (const float*)d_in[5];   // (B,3,KP,K)
    const int*   kptr = (const int*)d_in[6];     // scalar k
    const float* srcT = (const float*)d_in[7];   // (B,3,N)
    const float* tgtT = (const float*)d_in[8];   // (B,3,N)
    float* out = (float*)d_out;

    const int knn_quads  = in_sizes[4] / 4;                 // 49152
    const int knn_blocks = (knn_quads + 255) / 256;         // 192
    const int kp_blocks  = (NB * KP + 255) / 256;           // 8

    const size_t pts_bytes = (size_t)TOT_PTS * 16;          // 512 KB
    const size_t min_bytes = (size_t)TOT_PTS * 4;           // 128 KB
    const size_t ws_need   = pts_bytes + min_bytes + 64;
    if (ws_size >= ws_need) {
        float4*   pts4   = (float4*)d_ws;
        unsigned* minarr = (unsigned*)((char*)d_ws + pts_bytes);
        unsigned* ctrl   = (unsigned*)((char*)d_ws + pts_bytes + min_bytes);
        float*    acc    = (float*)&ctrl[0];
        unsigned* cnt    = &ctrl[1];
        prep_kernel<<<HALF_PTS / 256, 256, 0, stream>>>(srcT, tgtT, pts4, minarr, ctrl);
        main_kernel<<<512 + knn_blocks + kp_blocks, 256, 0, stream>>>(
            pts4, minarr, skp, tkp, R, T, aknn, bknn, kptr, acc, cnt, out,
            knn_blocks, knn_quads);
    } else {
        zero_out_kernel<<<1, 64, 0, stream>>>(out);
        gal_direct_kernel<<<dim3(NPTS / 256, 2 * NB), 256, 0, stream>>>(srcT, tgtT, out + 1);
        kp_kernel<<<kp_blocks, 256, 0, stream>>>(skp, tkp, R, T, out);
        knn_kernel<<<knn_blocks, 256, 0, stream>>>(aknn, bknn, kptr, out, knn_quads);
    }
}

// Round 4
// 94.818 us; speedup vs baseline: 1.2231x; 1.2231x over previous
//
#include <hip/hip_runtime.h>

#define NPTS 4096      // points per cloud
#define NB   4         // batch
#define KP   512       // keypoints
#define HUBER_C 0.01f
#define HALF_PTS (NB * NPTS)          // 16384
#define TOT_PTS  (2 * NB * NPTS)      // 32768
#define GAL_BLOCKS 1024               // 2 dir * 4 b * 4 qchunk * 32 ostripe
#define OSTRIPE 128                   // others per stripe
#define QPT 4                         // queries per thread

// ws layout:
//   [0,      512 KB)  float4 pts4[TOT_PTS]  {x,y,z,|p|^2}, src then tgt
//   [512 KB, 640 KB)  unsigned minarr[TOT_PTS]
//   [640 KB, +64 B )  ctrl: [0]=float acc (nc loss)

// ---------------- helpers ----------------

__device__ inline void wave_reduce_add_to(float v, float* target) {
    #pragma unroll
    for (int off = 32; off; off >>= 1) v += __shfl_down(v, off, 64);
    if ((threadIdx.x & 63) == 0) atomicAdd(target, v);
}

__device__ inline float huber_f(float x) {
    return (x < HUBER_C) ? 0.5f * x * x
                         : fmaf(HUBER_C, x, -0.5f * HUBER_C * HUBER_C);
}

// ---------------- kernels ----------------

// grid = HALF_PTS/256 = 64 blocks. Builds pts4, inits minarr, zeroes acc.
__global__ __launch_bounds__(256) void prep_kernel(
    const float* __restrict__ srcT, const float* __restrict__ tgtT,
    float4* __restrict__ pts4, unsigned* __restrict__ minarr,
    unsigned* __restrict__ ctrl)
{
    int i = blockIdx.x * 256 + threadIdx.x;    // [0, HALF_PTS)
    int b = i >> 12, j = i & (NPTS - 1);
    const float* s = srcT + b * 3 * NPTS;
    const float* t = tgtT + b * 3 * NPTS;
    float sx = s[j], sy = s[NPTS + j], sz = s[2 * NPTS + j];
    float tx = t[j], ty = t[NPTS + j], tz = t[2 * NPTS + j];
    pts4[i]            = make_float4(sx, sy, sz, fmaf(sx, sx, fmaf(sy, sy, sz * sz)));
    pts4[HALF_PTS + i] = make_float4(tx, ty, tz, fmaf(tx, tx, fmaf(ty, ty, tz * tz)));
    minarr[i] = 0x7F800000u;                  // +inf
    minarr[HALF_PTS + i] = 0x7F800000u;
    if (i == 0) ctrl[0] = 0u;                 // acc = 0.0f
}

// Fused main: blocks [0,GAL_BLOCKS) gal pairwise-min; then knn; then kp.
__global__ __launch_bounds__(256) void main_kernel(
    const float4* __restrict__ pts4, unsigned* __restrict__ minarr,
    const float* __restrict__ skp, const float* __restrict__ tkp,
    const float* __restrict__ R, const float* __restrict__ T,
    const float* __restrict__ aknn, const float* __restrict__ bknn,
    const int* __restrict__ kptr, float* __restrict__ acc,
    int knn_blocks, int knn_quads)
{
    const int bid = blockIdx.x;
    const int tid = threadIdx.x;

    if (bid < GAL_BLOCKS) {
        // ---- global-align pairwise min ----
        const int oc  = bid & 31;              // 32 other-stripes of 128
        const int b   = (bid >> 5) & 3;
        const int dir = (bid >> 7) & 1;        // 0: queries=src, 1: queries=tgt
        const int qc  = bid >> 8;              // 4 query-chunks of 1024
        const float4* q4 = pts4 + (dir ? HALF_PTS : 0) + b * NPTS + qc * 1024;
        const float4* o4 = pts4 + (dir ? 0 : HALF_PTS) + b * NPTS + oc * OSTRIPE;

        float ax[QPT], ay[QPT], az[QPT], qw[QPT], mm[QPT];
        #pragma unroll
        for (int q = 0; q < QPT; ++q) {
            float4 Q = q4[tid + q * 256];
            ax[q] = -2.0f * Q.x; ay[q] = -2.0f * Q.y; az[q] = -2.0f * Q.z;
            qw[q] = Q.w; mm[q] = 3.0e38f;
        }

        auto step2 = [&](float4 u, float4 v) {
            #pragma unroll
            for (int q = 0; q < QPT; ++q) {
                float t0 = fmaf(u.x, ax[q], fmaf(u.y, ay[q], fmaf(u.z, az[q], u.w)));
                float t1 = fmaf(v.x, ax[q], fmaf(v.y, ay[q], fmaf(v.z, az[q], v.w)));
                mm[q] = fminf(mm[q], fminf(t0, t1));     // v_min3_f32
            }
        };

        #pragma unroll 4
        for (int j = 0; j < OSTRIPE; j += 4) {
            float4 o0 = o4[j], o1 = o4[j + 1], o2 = o4[j + 2], o3 = o4[j + 3];
            step2(o0, o1);
            step2(o2, o3);
        }

        unsigned* marr = minarr + (dir * NB + b) * NPTS + qc * 1024 + tid;
        #pragma unroll
        for (int q = 0; q < QPT; ++q) {
            float d = fmaxf(qw[q] + mm[q], 0.0f);   // >=0: uint atomicMin order-safe
            atomicMin(&marr[q * 256], __float_as_uint(d));
        }
    } else if (bid < GAL_BLOCKS + knn_blocks) {
        // ---- knn consensus: sum((a-b)^2)/k ----
        int i = (bid - GAL_BLOCKS) * 256 + tid;
        float sum = 0.0f;
        if (i < knn_quads) {
            float4 va = ((const float4*)aknn)[i];
            float4 vb = ((const float4*)bknn)[i];
            float dx = va.x - vb.x, dy = va.y - vb.y;
            float dz = va.z - vb.z, dw = va.w - vb.w;
            sum = fmaf(dx, dx, fmaf(dy, dy, fmaf(dz, dz, dw * dw)));
        }
        float scale = 1.0f / (float)(*kptr);
        wave_reduce_add_to(sum * scale, acc);
    } else {
        // ---- keypoints: sum((R@s + t - g)^2) ----
        int i = (bid - GAL_BLOCKS - knn_blocks) * 256 + tid;   // [0, NB*KP)
        int b = i >> 9;
        int n = i & (KP - 1);
        const float* r = R + b * 9;
        const float* t = T + b * 3;
        const float* s = skp + b * 3 * KP;
        const float* g = tkp + b * 3 * KP;
        float sx = s[n], sy = s[KP + n], sz = s[2 * KP + n];
        float sum = 0.0f;
        #pragma unroll
        for (int d = 0; d < 3; ++d) {
            float v = fmaf(r[d*3+0], sx, fmaf(r[d*3+1], sy, fmaf(r[d*3+2], sz, t[d])))
                      - g[d * KP + n];
            sum = fmaf(v, v, sum);
        }
        wave_reduce_add_to(sum, acc);
    }
}

// single block: huber over the 32768 mins, write both outputs
__global__ __launch_bounds__(256) void finalize_kernel(
    const unsigned* __restrict__ minarr, const float* __restrict__ acc,
    float* __restrict__ out)
{
    __shared__ float red[4];
    const int tid = threadIdx.x;
    const uint4* m4 = (const uint4*)minarr;
    float sum = 0.0f;
    #pragma unroll
    for (int r = 0; r < 32; ++r) {           // 256 thr * 32 * uint4 = 32768
        uint4 v = m4[r * 256 + tid];
        sum += huber_f(__uint_as_float(v.x)) + huber_f(__uint_as_float(v.y))
             + huber_f(__uint_as_float(v.z)) + huber_f(__uint_as_float(v.w));
    }
    #pragma unroll
    for (int off = 32; off; off >>= 1) sum += __shfl_down(sum, off, 64);
    if ((tid & 63) == 0) red[tid >> 6] = sum;
    __syncthreads();
    if (tid == 0) {
        out[1] = red[0] + red[1] + red[2] + red[3];  // gal
        out[0] = *acc;                               // neighborhood consensus
    }
}

// ---------------- fallback (no workspace) ----------------

__global__ void zero_out_kernel(float* __restrict__ out) {
    if (threadIdx.x < 2) out[threadIdx.x] = 0.0f;
}

__global__ __launch_bounds__(256) void gal_direct_kernel(
    const float* __restrict__ srcT, const float* __restrict__ tgtT,
    float* __restrict__ gal_out)
{
    const int dir = blockIdx.y >> 2;
    const int b   = blockIdx.y & 3;
    const float* qb = (dir ? tgtT : srcT) + b * 3 * NPTS;
    const float* ob = (dir ? srcT : tgtT) + b * 3 * NPTS;
    const int qi = blockIdx.x * 256 + threadIdx.x;
    const float qx = qb[qi], qy = qb[NPTS + qi], qz = qb[2 * NPTS + qi];
    float m = 3.0e38f;
    #pragma unroll 4
    for (int j = 0; j < NPTS; ++j) {
        float dx = qx - ob[j], dy = qy - ob[NPTS + j], dz = qz - ob[2 * NPTS + j];
        m = fminf(m, fmaf(dx, dx, fmaf(dy, dy, dz * dz)));
    }
    wave_reduce_add_to(huber_f(m), gal_out);
}

__global__ __launch_bounds__(256) void kp_kernel(
    const float* __restrict__ skp, const float* __restrict__ tkp,
    const float* __restrict__ R, const float* __restrict__ T,
    float* __restrict__ acc)
{
    int i = blockIdx.x * 256 + threadIdx.x;
    int b = i >> 9, n = i & (KP - 1);
    const float* r = R + b * 9;
    const float* t = T + b * 3;
    const float* s = skp + b * 3 * KP;
    const float* g = tkp + b * 3 * KP;
    float sx = s[n], sy = s[KP + n], sz = s[2 * KP + n];
    float sum = 0.0f;
    #pragma unroll
    for (int d = 0; d < 3; ++d) {
        float v = fmaf(r[d*3+0], sx, fmaf(r[d*3+1], sy, fmaf(r[d*3+2], sz, t[d])))
                  - g[d * KP + n];
        sum = fmaf(v, v, sum);
    }
    wave_reduce_add_to(sum, acc);
}

__global__ __launch_bounds__(256) void knn_kernel(
    const float* __restrict__ a, const float* __restrict__ b,
    const int* __restrict__ kptr, float* __restrict__ acc, int quads)
{
    int i = blockIdx.x * 256 + threadIdx.x;
    float sum = 0.0f;
    if (i < quads) {
        float4 va = ((const float4*)a)[i];
        float4 vb = ((const float4*)b)[i];
        float dx = va.x - vb.x, dy = va.y - vb.y;
        float dz = va.z - vb.z, dw = va.w - vb.w;
        sum = fmaf(dx, dx, fmaf(dy, dy, fmaf(dz, dz, dw * dw)));
    }
    float scale = 1.0f / (float)(*kptr);
    wave_reduce_add_to(sum * scale, acc);
}

// ---------------- launch ----------------

extern "C" void kernel_launch(void* const* d_in, const int* in_sizes, int n_in,
                              void* d_out, int out_size, void* d_ws, size_t ws_size,
                              hipStream_t stream) {
    const float* skp  = (const float*)d_in[0];   // (B,3,KP)
    const float* tkp  = (const float*)d_in[1];   // (B,3,KP)
    const float* R    = (const float*)d_in[2];   // (B,3,3)
    const float* T    = (const float*)d_in[3];   // (B,3)
    const float* aknn = (const float*)d_in[4];   // (B,3,KP,K)
    const float* bknn = (const float*)d_in[5];   // (B,3,KP,K)
    const int*   kptr = (const int*)d_in[6];     // scalar k
    const float* srcT = (const float*)d_in[7];   // (B,3,N)
    const float* tgtT = (const float*)d_in[8];   // (B,3,N)
    float* out = (float*)d_out;

    const int knn_quads  = in_sizes[4] / 4;                 // 49152
    const int knn_blocks = (knn_quads + 255) / 256;         // 192
    const int kp_blocks  = (NB * KP + 255) / 256;           // 8

    const size_t pts_bytes = (size_t)TOT_PTS * 16;          // 512 KB
    const size_t min_bytes = (size_t)TOT_PTS * 4;           // 128 KB
    const size_t ws_need   = pts_bytes + min_bytes + 64;
    if (ws_size >= ws_need) {
        float4*   pts4   = (float4*)d_ws;
        unsigned* minarr = (unsigned*)((char*)d_ws + pts_bytes);
        unsigned* ctrl   = (unsigned*)((char*)d_ws + pts_bytes + min_bytes);
        float*    acc    = (float*)&ctrl[0];
        prep_kernel<<<HALF_PTS / 256, 256, 0, stream>>>(srcT, tgtT, pts4, minarr, ctrl);
        main_kernel<<<GAL_BLOCKS + knn_blocks + kp_blocks, 256, 0, stream>>>(
            pts4, minarr, skp, tkp, R, T, aknn, bknn, kptr, acc,
            knn_blocks, knn_quads);
        finalize_kernel<<<1, 256, 0, stream>>>(minarr, acc, out);
    } else {
        zero_out_kernel<<<1, 64, 0, stream>>>(out);
        gal_direct_kernel<<<dim3(NPTS / 256, 2 * NB), 256, 0, stream>>>(srcT, tgtT, out + 1);
        kp_kernel<<<kp_blocks, 256, 0, stream>>>(skp, tkp, R, T, out);
        knn_kernel<<<knn_blocks, 256, 0, stream>>>(aknn, bknn, kptr, out, knn_quads);
    }
}